// Round 4
// baseline (536.347 us; speedup 1.0000x reference)
//
#include <hip/hip_runtime.h>
#include <hip/hip_bf16.h>

#define N 8192
#define HID 64
#define RJC 8      // J-chunks for rowsum kernel: grid = 128*RJC
#define QCAP 2048  // LDS nonzero queue (expected ~164/block, 2048 = huge margin)

typedef __attribute__((ext_vector_type(4))) float f32x4;
typedef __attribute__((ext_vector_type(8))) __bf16 bf16x8;

// ---------------- Kernel A: projection + L2 normalize -> bf16 ----------------
__global__ __launch_bounds__(256) void proj_kernel(
    const float* __restrict__ x1, const float* __restrict__ x2,
    const float* __restrict__ W1, const float* __restrict__ b1,
    const float* __restrict__ W2, const float* __restrict__ b2,
    __bf16* __restrict__ Z1h, __bf16* __restrict__ Z2h)
{
  __shared__ __align__(16) float w1s[64*68];
  __shared__ __align__(16) float w2s[64*68];
  __shared__ __align__(16) float xs[4][64];
  __shared__ __align__(16) float hs[4][64];

  const int tid  = threadIdx.x;
  const int lane = tid & 63;
  const int w    = tid >> 6;

  for (int idx = tid; idx < 64*64; idx += 256) {
    int j = idx >> 6, k = idx & 63;
    w1s[j*68+k] = W1[idx];
    w2s[j*68+k] = W2[idx];
  }
  __syncthreads();

  const float bias1 = b1[lane];
  const float bias2 = b2[lane];

  const int wave_global = blockIdx.x * 4 + w;   // 0..4095 with grid=1024
  #pragma unroll 1
  for (int it = 0; it < 4; ++it) {
    int R = wave_global * 4 + it;               // 0..16383
    const float* src; __bf16* dst;
    if (R < N) { src = x1 + (size_t)R*HID;      dst = Z1h + (size_t)R*HID; }
    else       { src = x2 + (size_t)(R-N)*HID;  dst = Z2h + (size_t)(R-N)*HID; }

    float xv = src[lane];
    xs[w][lane] = xv;
    float acc = bias1;
    #pragma unroll
    for (int qq = 0; qq < 16; ++qq) {
      f32x4 xq = *(const f32x4*)&xs[w][qq*4];            // broadcast read
      f32x4 wq = *(const f32x4*)&w1s[lane*68 + qq*4];
      acc += xq.x*wq.x + xq.y*wq.y + xq.z*wq.z + xq.w*wq.w;
    }
    float h = acc > 0.f ? acc : expm1f(acc);             // ELU (alpha=1)
    hs[w][lane] = h;
    float acc2 = bias2;
    #pragma unroll
    for (int qq = 0; qq < 16; ++qq) {
      f32x4 hq = *(const f32x4*)&hs[w][qq*4];
      f32x4 wq = *(const f32x4*)&w2s[lane*68 + qq*4];
      acc2 += hq.x*wq.x + hq.y*wq.y + hq.z*wq.z + hq.w*wq.w;
    }
    float z = acc2;
    float ss = z*z;
    #pragma unroll
    for (int m = 1; m < 64; m <<= 1) ss += __shfl_xor(ss, m);
    float inv = 1.0f / fmaxf(sqrtf(ss), 1e-12f);
    dst[lane] = (__bf16)(z * inv);
  }
}

// ---------------- num contribution for one nonzero pos entry ----------------
__device__ __forceinline__ void process_pair(
    int f, const __bf16* __restrict__ Z1h, const __bf16* __restrict__ Z2h,
    float* __restrict__ num1, float* __restrict__ num2)
{
  const float Cexp = 1.8033688011112042f;  // 1/(TAU*ln2), TAU=0.8
  int i = f >> 13, j = f & (N-1);
  const __bf16* a1 = Z1h + (size_t)i*HID;  // sim1[i][j] = z1[i].z2[j]
  const __bf16* b2 = Z2h + (size_t)j*HID;
  const __bf16* a2 = Z2h + (size_t)i*HID;  // sim2[i][j] = z2[i].z1[j]
  const __bf16* b1 = Z1h + (size_t)j*HID;
  float d1 = 0.f, d2 = 0.f;
  #pragma unroll
  for (int c = 0; c < 8; ++c) {
    bf16x8 va1 = *(const bf16x8*)(a1 + c*8);
    bf16x8 vb2 = *(const bf16x8*)(b2 + c*8);
    bf16x8 va2 = *(const bf16x8*)(a2 + c*8);
    bf16x8 vb1 = *(const bf16x8*)(b1 + c*8);
    #pragma unroll
    for (int e = 0; e < 8; ++e) {
      d1 += (float)va1[e] * (float)vb2[e];
      d2 += (float)va2[e] * (float)vb1[e];
    }
  }
  atomicAdd(&num1[i], exp2f(d1 * Cexp));
  atomicAdd(&num2[i], exp2f(d2 * Cexp));
}

// ---------------- Kernel B1: stream pos, compact nonzeros, accumulate num ---
// pos is binary (0/1) with ~0.5% density. Pure-coalesced float4 stream
// (block-contiguous 128 KB chunks -> memcpy-like HBM pattern), nonzero flat
// indices pushed to an LDS queue, then one compact pass does the dots.
__global__ __launch_bounds__(256) void scan_kernel(
    const float* __restrict__ pos,
    const __bf16* __restrict__ Z1h, const __bf16* __restrict__ Z2h,
    float* __restrict__ num1, float* __restrict__ num2)
{
  __shared__ int q_cnt;
  __shared__ int q_idx[QCAP];
  const int tid = threadIdx.x;
  if (tid == 0) q_cnt = 0;
  __syncthreads();

  const size_t base = (size_t)blockIdx.x * 32768;   // 2048 blocks x 32K floats
  #pragma unroll 2
  for (int it = 0; it < 32; ++it) {
    size_t off = base + (size_t)it*1024 + (size_t)tid*4;
    f32x4 v = *(const f32x4*)(pos + off);
    if (v.x != 0.f || v.y != 0.f || v.z != 0.f || v.w != 0.f) {
      #pragma unroll
      for (int c = 0; c < 4; ++c) {
        float vc = (c==0)?v.x:(c==1)?v.y:(c==2)?v.z:v.w;
        if (vc != 0.f) {
          int slot = atomicAdd(&q_cnt, 1);
          if (slot < QCAP) q_idx[slot] = (int)off + c;
          else process_pair((int)off + c, Z1h, Z2h, num1, num2); // overflow fallback
        }
      }
    }
  }
  __syncthreads();
  int cnt = min(q_cnt, QCAP);
  for (int k = tid; k < cnt; k += 256)
    process_pair(q_idx[k], Z1h, Z2h, num1, num2);
}

// ---------------- Kernel B2: rowsum = full exp-sim row sums (no pos) --------
// Block = 64 I-rows x (N/RJC) J-cols. B-tiles (64 J-rows of Z1 AND Z2) staged
// coalesced into LDS with row stride 72 bf16 (144 B): frag-read start bank =
// 4*((r16+q)&7) -> worst 2-way conflict (free, m136).
__global__ __launch_bounds__(256) void rowsum_kernel(
    const __bf16* __restrict__ Z1h, const __bf16* __restrict__ Z2h,
    float* __restrict__ rowsum1, float* __restrict__ rowsum2)
{
  __shared__ __align__(16) __bf16 s1[64*72];
  __shared__ __align__(16) __bf16 s2[64*72];

  const int tid  = threadIdx.x;
  const int lane = tid & 63;
  const int w    = tid >> 6;
  const int r16  = lane & 15;
  const int q    = lane >> 4;

  const int bi = blockIdx.x / RJC;
  const int jc = blockIdx.x % RJC;
  const int i0 = bi*64 + w*16;

  const __bf16* z1r = Z1h + (size_t)(i0 + r16)*HID + q*8;
  const __bf16* z2r = Z2h + (size_t)(i0 + r16)*HID + q*8;
  bf16x8 a1lo = *(const bf16x8*)(z1r);
  bf16x8 a1hi = *(const bf16x8*)(z1r + 32);
  bf16x8 a2lo = *(const bf16x8*)(z2r);
  bf16x8 a2hi = *(const bf16x8*)(z2r + 32);

  float sa1[4] = {0.f,0.f,0.f,0.f}, sa2[4] = {0.f,0.f,0.f,0.f};
  const float Cexp = 1.8033688011112042f;

  const int jbeg = jc * (N/RJC);
  const int jend = jbeg + (N/RJC);

  // staging descriptors: 512 16B-chunks per matrix, 2 per thread
  const int c0 = tid,       r0 = c0 >> 3, e0 = (c0 & 7) * 8;
  const int c1 = tid + 256, r1 = c1 >> 3, e1 = (c1 & 7) * 8;

  #pragma unroll 1
  for (int j0 = jbeg; j0 < jend; j0 += 64) {
    __syncthreads();   // previous iter's LDS reads done
    *(uint4*)&s1[r0*72 + e0] = *(const uint4*)(Z1h + (size_t)(j0 + r0)*HID + e0);
    *(uint4*)&s1[r1*72 + e1] = *(const uint4*)(Z1h + (size_t)(j0 + r1)*HID + e1);
    *(uint4*)&s2[r0*72 + e0] = *(const uint4*)(Z2h + (size_t)(j0 + r0)*HID + e0);
    *(uint4*)&s2[r1*72 + e1] = *(const uint4*)(Z2h + (size_t)(j0 + r1)*HID + e1);
    __syncthreads();

    const f32x4 zero4 = {0.f,0.f,0.f,0.f};
    #pragma unroll
    for (int c = 0; c < 4; ++c) {
      const __bf16* p2 = &s2[(c*16 + r16)*72 + q*8];
      const __bf16* p1 = &s1[(c*16 + r16)*72 + q*8];
      bf16x8 b2lo = *(const bf16x8*)(p2);
      bf16x8 b2hi = *(const bf16x8*)(p2 + 32);
      bf16x8 b1lo = *(const bf16x8*)(p1);
      bf16x8 b1hi = *(const bf16x8*)(p1 + 32);
      f32x4 d1 = __builtin_amdgcn_mfma_f32_16x16x32_bf16(a1lo, b2lo, zero4, 0,0,0);
      d1       = __builtin_amdgcn_mfma_f32_16x16x32_bf16(a1hi, b2hi, d1,    0,0,0);
      f32x4 d2 = __builtin_amdgcn_mfma_f32_16x16x32_bf16(a2lo, b1lo, zero4, 0,0,0);
      d2       = __builtin_amdgcn_mfma_f32_16x16x32_bf16(a2hi, b1hi, d2,    0,0,0);
      #pragma unroll
      for (int r = 0; r < 4; ++r) {
        sa1[r] += exp2f(d1[r] * Cexp);
        sa2[r] += exp2f(d2[r] * Cexp);
      }
    }
  }

  #pragma unroll
  for (int r = 0; r < 4; ++r) {
    #pragma unroll
    for (int m = 1; m < 16; m <<= 1) {
      sa1[r] += __shfl_xor(sa1[r], m);
      sa2[r] += __shfl_xor(sa2[r], m);
    }
  }
  if (r16 == 0) {
    #pragma unroll
    for (int r = 0; r < 4; ++r) {
      int row = i0 + q*4 + r;
      atomicAdd(&rowsum1[row], sa1[r]);
      atomicAdd(&rowsum2[row], sa2[r]);
    }
  }
}

// ---------------- Kernel C: final loss reduction ----------------
__global__ __launch_bounds__(1024) void loss_kernel(
    const float* __restrict__ rowsum1, const float* __restrict__ num1,
    const float* __restrict__ rowsum2, const float* __restrict__ num2,
    float* __restrict__ out)
{
  __shared__ float part[16];
  const int tid = threadIdx.x, lane = tid & 63, w = tid >> 6;
  float acc = 0.f;
  for (int i = tid; i < N; i += 1024) {
    float sc = -logf(num1[i]/(rowsum1[i]+1e-8f) + 1e-8f);
    float mp = -logf(num2[i]/(rowsum2[i]+1e-8f) + 1e-8f);
    acc += 0.5f*sc + 0.5f*mp;   // LAMBDA = 0.5
  }
  #pragma unroll
  for (int m = 1; m < 64; m <<= 1) acc += __shfl_xor(acc, m);
  if (lane == 0) part[w] = acc;
  __syncthreads();
  if (tid == 0) {
    float t = 0.f;
    #pragma unroll
    for (int k = 0; k < 16; ++k) t += part[k];
    out[0] = t * (1.0f/N);
  }
}

extern "C" void kernel_launch(void* const* d_in, const int* in_sizes, int n_in,
                              void* d_out, int out_size, void* d_ws, size_t ws_size,
                              hipStream_t stream) {
  const float* x1  = (const float*)d_in[0];
  const float* x2  = (const float*)d_in[1];
  const float* W1  = (const float*)d_in[2];
  const float* b1  = (const float*)d_in[3];
  const float* W2  = (const float*)d_in[4];
  const float* b2  = (const float*)d_in[5];
  const float* pos = (const float*)d_in[6];

  char* ws = (char*)d_ws;
  __bf16* Z1h = (__bf16*)ws;
  __bf16* Z2h = (__bf16*)(ws + (size_t)N*HID*sizeof(__bf16));
  size_t zbytes = (size_t)2*N*HID*sizeof(__bf16);   // 2 MB
  float* rowsum1 = (float*)(ws + zbytes);
  float* num1    = rowsum1 + N;
  float* rowsum2 = num1 + N;
  float* num2    = rowsum2 + N;

  hipMemsetAsync(ws + zbytes, 0, (size_t)4*N*sizeof(float), stream);
  proj_kernel<<<1024, 256, 0, stream>>>(x1, x2, W1, b1, W2, b2, Z1h, Z2h);
  scan_kernel<<<2048, 256, 0, stream>>>(pos, Z1h, Z2h, num1, num2);
  rowsum_kernel<<<128*RJC, 256, 0, stream>>>(Z1h, Z2h, rowsum1, rowsum2);
  loss_kernel<<<1, 1024, 0, stream>>>(rowsum1, num1, rowsum2, num2, (float*)d_out);
}

// Round 5
// 514.558 us; speedup vs baseline: 1.0423x; 1.0423x over previous
//
#include <hip/hip_runtime.h>
#include <hip/hip_bf16.h>

#define N 8192
#define HID 64
#define SCAN_BLOCKS 2048
#define ROWSUM_BLOCKS 1024   // RJC=8 -> 128 I-tiles x 8 J-chunks
#define RJC 8
#define QCAP 2048            // expected ~168 nonzeros/block, huge margin

typedef __attribute__((ext_vector_type(4))) float f32x4;
typedef __attribute__((ext_vector_type(4))) unsigned int u32x4;
typedef __attribute__((ext_vector_type(8))) __bf16 bf16x8;

// ---------------- Kernel A: projection + L2 normalize -> bf16 ----------------
__global__ __launch_bounds__(256) void proj_kernel(
    const float* __restrict__ x1, const float* __restrict__ x2,
    const float* __restrict__ W1, const float* __restrict__ b1,
    const float* __restrict__ W2, const float* __restrict__ b2,
    __bf16* __restrict__ Z1h, __bf16* __restrict__ Z2h)
{
  __shared__ __align__(16) float w1s[64*68];
  __shared__ __align__(16) float w2s[64*68];
  __shared__ __align__(16) float xs[4][64];
  __shared__ __align__(16) float hs[4][64];

  const int tid  = threadIdx.x;
  const int lane = tid & 63;
  const int w    = tid >> 6;

  for (int idx = tid; idx < 64*64; idx += 256) {
    int j = idx >> 6, k = idx & 63;
    w1s[j*68+k] = W1[idx];
    w2s[j*68+k] = W2[idx];
  }
  __syncthreads();

  const float bias1 = b1[lane];
  const float bias2 = b2[lane];

  const int wave_global = blockIdx.x * 4 + w;   // 0..4095 with grid=1024
  #pragma unroll 1
  for (int it = 0; it < 4; ++it) {
    int R = wave_global * 4 + it;               // 0..16383
    const float* src; __bf16* dst;
    if (R < N) { src = x1 + (size_t)R*HID;      dst = Z1h + (size_t)R*HID; }
    else       { src = x2 + (size_t)(R-N)*HID;  dst = Z2h + (size_t)(R-N)*HID; }

    float xv = src[lane];
    xs[w][lane] = xv;
    float acc = bias1;
    #pragma unroll
    for (int qq = 0; qq < 16; ++qq) {
      f32x4 xq = *(const f32x4*)&xs[w][qq*4];            // broadcast read
      f32x4 wq = *(const f32x4*)&w1s[lane*68 + qq*4];
      acc += xq.x*wq.x + xq.y*wq.y + xq.z*wq.z + xq.w*wq.w;
    }
    float h = acc > 0.f ? acc : expm1f(acc);             // ELU (alpha=1)
    hs[w][lane] = h;
    float acc2 = bias2;
    #pragma unroll
    for (int qq = 0; qq < 16; ++qq) {
      f32x4 hq = *(const f32x4*)&hs[w][qq*4];
      f32x4 wq = *(const f32x4*)&w2s[lane*68 + qq*4];
      acc2 += hq.x*wq.x + hq.y*wq.y + hq.z*wq.z + hq.w*wq.w;
    }
    float z = acc2;
    float ss = z*z;
    #pragma unroll
    for (int m = 1; m < 64; m <<= 1) ss += __shfl_xor(ss, m);
    float inv = 1.0f / fmaxf(sqrtf(ss), 1e-12f);
    dst[lane] = (__bf16)(z * inv);
  }
}

// ---------------- num contribution for one nonzero pos entry ----------------
__device__ __forceinline__ void process_pair(
    int f, const __bf16* __restrict__ Z1h, const __bf16* __restrict__ Z2h,
    float* __restrict__ num1, float* __restrict__ num2)
{
  const float Cexp = 1.8033688011112042f;  // 1/(TAU*ln2), TAU=0.8
  int i = f >> 13, j = f & (N-1);
  const __bf16* a1 = Z1h + (size_t)i*HID;  // sim1[i][j] = z1[i].z2[j]
  const __bf16* b2 = Z2h + (size_t)j*HID;
  const __bf16* a2 = Z2h + (size_t)i*HID;  // sim2[i][j] = z2[i].z1[j]
  const __bf16* b1 = Z1h + (size_t)j*HID;
  float d1 = 0.f, d2 = 0.f;
  #pragma unroll
  for (int c = 0; c < 8; ++c) {
    bf16x8 va1 = *(const bf16x8*)(a1 + c*8);
    bf16x8 vb2 = *(const bf16x8*)(b2 + c*8);
    bf16x8 va2 = *(const bf16x8*)(a2 + c*8);
    bf16x8 vb1 = *(const bf16x8*)(b1 + c*8);
    #pragma unroll
    for (int e = 0; e < 8; ++e) {
      d1 += (float)va1[e] * (float)vb2[e];
      d2 += (float)va2[e] * (float)vb1[e];
    }
  }
  atomicAdd(&num1[i], exp2f(d1 * Cexp));
  atomicAdd(&num2[i], exp2f(d2 * Cexp));
}

// ---------------- Fused kernel: scan (mem-bound) + rowsum (compute-bound) ---
// blockIdx % 3 in {0,1} -> scan block (2048 total): batched 8x dwordx4 pos
// stream (8 KB/wave in flight), compact nonzero indices to LDS, drain with
// process_pair. blockIdx % 3 == 2 -> rowsum block (1024): LDS-staged MFMA
// exp-row-sums. Interleave keeps both species co-resident on every CU.
__global__ __launch_bounds__(256) void fused_kernel(
    const float* __restrict__ pos,
    const __bf16* __restrict__ Z1h, const __bf16* __restrict__ Z2h,
    float* __restrict__ rowsum1, float* __restrict__ num1,
    float* __restrict__ rowsum2, float* __restrict__ num2)
{
  __shared__ int q_cnt;
  __shared__ int q_idx[QCAP];
  __shared__ __align__(16) __bf16 s1[64*72];
  __shared__ __align__(16) __bf16 s2[64*72];

  const int tid = threadIdx.x;
  const int rsel = blockIdx.x % 3;

  if (rsel < 2) {
    // ================= SCAN =================
    const int sb = (blockIdx.x / 3) * 2 + rsel;   // 0..2047
    if (tid == 0) q_cnt = 0;
    __syncthreads();

    const float* p = pos + (size_t)sb * 32768;
    #pragma unroll 1
    for (int it = 0; it < 4; ++it) {
      u32x4 v[8];
      #pragma unroll
      for (int k = 0; k < 8; ++k)
        v[k] = *(const u32x4*)(p + it*8192 + k*1024 + tid*4);   // 8 loads in flight
      #pragma unroll
      for (int k = 0; k < 8; ++k) {
        unsigned int any = v[k].x | v[k].y | v[k].z | v[k].w;
        if (any) {
          int off = sb*32768 + it*8192 + k*1024 + tid*4;
          #pragma unroll
          for (int c = 0; c < 4; ++c) {
            unsigned int vc = (c==0)?v[k].x:(c==1)?v[k].y:(c==2)?v[k].z:v[k].w;
            if (vc) {
              int slot = atomicAdd(&q_cnt, 1);
              if (slot < QCAP) q_idx[slot] = off + c;
            }
          }
        }
      }
    }
    __syncthreads();
    int cnt = min(q_cnt, QCAP);
    for (int k = tid; k < cnt; k += 256)
      process_pair(q_idx[k], Z1h, Z2h, num1, num2);
  } else {
    // ================= ROWSUM =================
    const int rb   = blockIdx.x / 3;        // 0..1023
    const int lane = tid & 63;
    const int w    = tid >> 6;
    const int r16  = lane & 15;
    const int q    = lane >> 4;

    const int bi = rb / RJC;
    const int jc = rb % RJC;
    const int i0 = bi*64 + w*16;

    const __bf16* z1r = Z1h + (size_t)(i0 + r16)*HID + q*8;
    const __bf16* z2r = Z2h + (size_t)(i0 + r16)*HID + q*8;
    bf16x8 a1lo = *(const bf16x8*)(z1r);
    bf16x8 a1hi = *(const bf16x8*)(z1r + 32);
    bf16x8 a2lo = *(const bf16x8*)(z2r);
    bf16x8 a2hi = *(const bf16x8*)(z2r + 32);

    float sa1[4] = {0.f,0.f,0.f,0.f}, sa2[4] = {0.f,0.f,0.f,0.f};
    const float Cexp = 1.8033688011112042f;

    const int jbeg = jc * (N/RJC);
    const int jend = jbeg + (N/RJC);

    const int c0 = tid,       r0 = c0 >> 3, e0 = (c0 & 7) * 8;
    const int c1 = tid + 256, r1 = c1 >> 3, e1 = (c1 & 7) * 8;

    #pragma unroll 1
    for (int j0 = jbeg; j0 < jend; j0 += 64) {
      __syncthreads();   // previous iter's LDS reads done
      *(uint4*)&s1[r0*72 + e0] = *(const uint4*)(Z1h + (size_t)(j0 + r0)*HID + e0);
      *(uint4*)&s1[r1*72 + e1] = *(const uint4*)(Z1h + (size_t)(j0 + r1)*HID + e1);
      *(uint4*)&s2[r0*72 + e0] = *(const uint4*)(Z2h + (size_t)(j0 + r0)*HID + e0);
      *(uint4*)&s2[r1*72 + e1] = *(const uint4*)(Z2h + (size_t)(j0 + r1)*HID + e1);
      __syncthreads();

      const f32x4 zero4 = {0.f,0.f,0.f,0.f};
      #pragma unroll
      for (int c = 0; c < 4; ++c) {
        const __bf16* p2 = &s2[(c*16 + r16)*72 + q*8];
        const __bf16* p1 = &s1[(c*16 + r16)*72 + q*8];
        bf16x8 b2lo = *(const bf16x8*)(p2);
        bf16x8 b2hi = *(const bf16x8*)(p2 + 32);
        bf16x8 b1lo = *(const bf16x8*)(p1);
        bf16x8 b1hi = *(const bf16x8*)(p1 + 32);
        f32x4 d1 = __builtin_amdgcn_mfma_f32_16x16x32_bf16(a1lo, b2lo, zero4, 0,0,0);
        d1       = __builtin_amdgcn_mfma_f32_16x16x32_bf16(a1hi, b2hi, d1,    0,0,0);
        f32x4 d2 = __builtin_amdgcn_mfma_f32_16x16x32_bf16(a2lo, b1lo, zero4, 0,0,0);
        d2       = __builtin_amdgcn_mfma_f32_16x16x32_bf16(a2hi, b1hi, d2,    0,0,0);
        #pragma unroll
        for (int r = 0; r < 4; ++r) {
          sa1[r] += exp2f(d1[r] * Cexp);
          sa2[r] += exp2f(d2[r] * Cexp);
        }
      }
    }

    #pragma unroll
    for (int r = 0; r < 4; ++r) {
      #pragma unroll
      for (int m = 1; m < 16; m <<= 1) {
        sa1[r] += __shfl_xor(sa1[r], m);
        sa2[r] += __shfl_xor(sa2[r], m);
      }
    }
    if (r16 == 0) {
      #pragma unroll
      for (int r = 0; r < 4; ++r) {
        int row = i0 + q*4 + r;
        atomicAdd(&rowsum1[row], sa1[r]);
        atomicAdd(&rowsum2[row], sa2[r]);
      }
    }
  }
}

// ---------------- Kernel C: final loss reduction ----------------
__global__ __launch_bounds__(1024) void loss_kernel(
    const float* __restrict__ rowsum1, const float* __restrict__ num1,
    const float* __restrict__ rowsum2, const float* __restrict__ num2,
    float* __restrict__ out)
{
  __shared__ float part[16];
  const int tid = threadIdx.x, lane = tid & 63, w = tid >> 6;
  float acc = 0.f;
  for (int i = tid; i < N; i += 1024) {
    float sc = -logf(num1[i]/(rowsum1[i]+1e-8f) + 1e-8f);
    float mp = -logf(num2[i]/(rowsum2[i]+1e-8f) + 1e-8f);
    acc += 0.5f*sc + 0.5f*mp;   // LAMBDA = 0.5
  }
  #pragma unroll
  for (int m = 1; m < 64; m <<= 1) acc += __shfl_xor(acc, m);
  if (lane == 0) part[w] = acc;
  __syncthreads();
  if (tid == 0) {
    float t = 0.f;
    #pragma unroll
    for (int k = 0; k < 16; ++k) t += part[k];
    out[0] = t * (1.0f/N);
  }
}

extern "C" void kernel_launch(void* const* d_in, const int* in_sizes, int n_in,
                              void* d_out, int out_size, void* d_ws, size_t ws_size,
                              hipStream_t stream) {
  const float* x1  = (const float*)d_in[0];
  const float* x2  = (const float*)d_in[1];
  const float* W1  = (const float*)d_in[2];
  const float* b1  = (const float*)d_in[3];
  const float* W2  = (const float*)d_in[4];
  const float* b2  = (const float*)d_in[5];
  const float* pos = (const float*)d_in[6];

  char* ws = (char*)d_ws;
  __bf16* Z1h = (__bf16*)ws;
  __bf16* Z2h = (__bf16*)(ws + (size_t)N*HID*sizeof(__bf16));
  size_t zbytes = (size_t)2*N*HID*sizeof(__bf16);   // 2 MB
  float* rowsum1 = (float*)(ws + zbytes);
  float* num1    = rowsum1 + N;
  float* rowsum2 = num1 + N;
  float* num2    = rowsum2 + N;

  hipMemsetAsync(ws + zbytes, 0, (size_t)4*N*sizeof(float), stream);
  proj_kernel<<<1024, 256, 0, stream>>>(x1, x2, W1, b1, W2, b2, Z1h, Z2h);
  fused_kernel<<<SCAN_BLOCKS/2*3, 256, 0, stream>>>(pos, Z1h, Z2h,
      rowsum1, num1, rowsum2, num2);
  loss_kernel<<<1, 1024, 0, stream>>>(rowsum1, num1, rowsum2, num2, (float*)d_out);
}

// Round 6
// 471.728 us; speedup vs baseline: 1.1370x; 1.0908x over previous
//
#include <hip/hip_runtime.h>
#include <hip/hip_bf16.h>

#define N 8192
#define HID 64
#define JC 16   // J-chunks per I-tile: grid = 128*JC blocks

typedef __attribute__((ext_vector_type(4))) float f32x4;
typedef __attribute__((ext_vector_type(8))) __bf16 bf16x8;

// ---------------- Kernel A: projection + L2 normalize -> bf16 ----------------
__global__ __launch_bounds__(256) void proj_kernel(
    const float* __restrict__ x1, const float* __restrict__ x2,
    const float* __restrict__ W1, const float* __restrict__ b1,
    const float* __restrict__ W2, const float* __restrict__ b2,
    __bf16* __restrict__ Z1h, __bf16* __restrict__ Z2h)
{
  __shared__ __align__(16) float w1s[64*68];
  __shared__ __align__(16) float w2s[64*68];
  __shared__ __align__(16) float xs[4][64];
  __shared__ __align__(16) float hs[4][64];

  const int tid  = threadIdx.x;
  const int lane = tid & 63;
  const int w    = tid >> 6;

  for (int idx = tid; idx < 64*64; idx += 256) {
    int j = idx >> 6, k = idx & 63;
    w1s[j*68+k] = W1[idx];
    w2s[j*68+k] = W2[idx];
  }
  __syncthreads();

  const float bias1 = b1[lane];
  const float bias2 = b2[lane];

  const int wave_global = blockIdx.x * 4 + w;   // 0..4095 with grid=1024
  #pragma unroll 1
  for (int it = 0; it < 4; ++it) {
    int R = wave_global * 4 + it;               // 0..16383
    const float* src; __bf16* dst;
    if (R < N) { src = x1 + (size_t)R*HID;      dst = Z1h + (size_t)R*HID; }
    else       { src = x2 + (size_t)(R-N)*HID;  dst = Z2h + (size_t)(R-N)*HID; }

    float xv = src[lane];
    xs[w][lane] = xv;
    float acc = bias1;
    #pragma unroll
    for (int qq = 0; qq < 16; ++qq) {
      f32x4 xq = *(const f32x4*)&xs[w][qq*4];            // broadcast read
      f32x4 wq = *(const f32x4*)&w1s[lane*68 + qq*4];
      acc += xq.x*wq.x + xq.y*wq.y + xq.z*wq.z + xq.w*wq.w;
    }
    float h = acc > 0.f ? acc : expm1f(acc);             // ELU (alpha=1)
    hs[w][lane] = h;
    float acc2 = bias2;
    #pragma unroll
    for (int qq = 0; qq < 16; ++qq) {
      f32x4 hq = *(const f32x4*)&hs[w][qq*4];
      f32x4 wq = *(const f32x4*)&w2s[lane*68 + qq*4];
      acc2 += hq.x*wq.x + hq.y*wq.y + hq.z*wq.z + hq.w*wq.w;
    }
    float z = acc2;
    float ss = z*z;
    #pragma unroll
    for (int m = 1; m < 64; m <<= 1) ss += __shfl_xor(ss, m);
    float inv = 1.0f / fmaxf(sqrtf(ss), 1e-12f);
    dst[lane] = (__bf16)(z * inv);
  }
}

// ---------------- Kernel B: tiled exp-sim accumulation (R2 champion) --------
// Identical to the R2 structure (162 us, absmax 0) EXCEPT: pos loads are
// NONTEMPORAL (nt bit -> no cache allocation). Theory: the harness's ~1 GB
// 0xAA workspace poison leaves dirty lines; cached pos fills evict them ->
// one HBM writeback per read line, halving the effective read BW. nt on the
// single-use pos stream removes the evictions. Z loads stay cached (reused).
__global__ __launch_bounds__(256, 6) void sim_kernel(
    const __bf16* __restrict__ Z1h, const __bf16* __restrict__ Z2h,
    const float* __restrict__ pos,
    float* __restrict__ rowsum1, float* __restrict__ num1,
    float* __restrict__ rowsum2, float* __restrict__ num2)
{
  const int tid  = threadIdx.x;
  const int lane = tid & 63;
  const int w    = tid >> 6;
  const int r16  = lane & 15;
  const int q    = lane >> 4;

  const int bi = blockIdx.x / JC;   // 0..127 I-tile
  const int jc = blockIdx.x % JC;
  const int i0 = bi*64 + w*16;

  const __bf16* z1r = Z1h + (size_t)(i0 + r16)*HID + q*8;
  const __bf16* z2r = Z2h + (size_t)(i0 + r16)*HID + q*8;
  bf16x8 a1lo = *(const bf16x8*)(z1r);
  bf16x8 a1hi = *(const bf16x8*)(z1r + 32);
  bf16x8 a2lo = *(const bf16x8*)(z2r);
  bf16x8 a2hi = *(const bf16x8*)(z2r + 32);

  float s1[4] = {0.f,0.f,0.f,0.f}, n1[4] = {0.f,0.f,0.f,0.f};
  float s2[4] = {0.f,0.f,0.f,0.f}, n2[4] = {0.f,0.f,0.f,0.f};

  const int jbeg = jc * (N/JC);
  const int jend = jbeg + (N/JC);
  const float Cexp = 1.8033688011112042f;  // 1/(TAU*ln2), TAU=0.8

  const float* pbase = pos + (size_t)(i0 + q*4)*N + r16;

  #pragma unroll 1
  for (int j0 = jbeg; j0 < jend; j0 += 32) {
    bf16x8 b2l[2], b2h[2], b1l[2], b1h[2];
    float pv[2][4];
    #pragma unroll
    for (int c = 0; c < 2; ++c) {
      const __bf16* zb2 = Z2h + (size_t)(j0 + c*16 + r16)*HID + q*8;
      const __bf16* zb1 = Z1h + (size_t)(j0 + c*16 + r16)*HID + q*8;
      b2l[c] = *(const bf16x8*)(zb2);
      b2h[c] = *(const bf16x8*)(zb2 + 32);
      b1l[c] = *(const bf16x8*)(zb1);
      b1h[c] = *(const bf16x8*)(zb1 + 32);
      const float* pp = pbase + j0 + c*16;
      pv[c][0] = __builtin_nontemporal_load(pp);
      pv[c][1] = __builtin_nontemporal_load(pp + (size_t)N);
      pv[c][2] = __builtin_nontemporal_load(pp + (size_t)2*N);
      pv[c][3] = __builtin_nontemporal_load(pp + (size_t)3*N);
    }
    #pragma unroll
    for (int c = 0; c < 2; ++c) {
      const f32x4 zero4 = {0.f,0.f,0.f,0.f};
      f32x4 d1 = __builtin_amdgcn_mfma_f32_16x16x32_bf16(a1lo, b2l[c], zero4, 0,0,0);
      d1       = __builtin_amdgcn_mfma_f32_16x16x32_bf16(a1hi, b2h[c], d1,    0,0,0);
      f32x4 d2 = __builtin_amdgcn_mfma_f32_16x16x32_bf16(a2lo, b1l[c], zero4, 0,0,0);
      d2       = __builtin_amdgcn_mfma_f32_16x16x32_bf16(a2hi, b1h[c], d2,    0,0,0);
      #pragma unroll
      for (int r = 0; r < 4; ++r) {
        float e1 = exp2f(d1[r] * Cexp);
        float e2 = exp2f(d2[r] * Cexp);
        s1[r] += e1; n1[r] += e1 * pv[c][r];
        s2[r] += e2; n2[r] += e2 * pv[c][r];
      }
    }
  }

  // reduce across the 16 lanes of each quad (cols), leaving per-row sums
  #pragma unroll
  for (int r = 0; r < 4; ++r) {
    #pragma unroll
    for (int m = 1; m < 16; m <<= 1) {
      s1[r] += __shfl_xor(s1[r], m);
      n1[r] += __shfl_xor(n1[r], m);
      s2[r] += __shfl_xor(s2[r], m);
      n2[r] += __shfl_xor(n2[r], m);
    }
  }
  if (r16 == 0) {
    #pragma unroll
    for (int r = 0; r < 4; ++r) {
      int row = i0 + q*4 + r;
      atomicAdd(&rowsum1[row], s1[r]);
      atomicAdd(&num1[row],    n1[r]);
      atomicAdd(&rowsum2[row], s2[r]);
      atomicAdd(&num2[row],    n2[r]);
    }
  }
}

// ---------------- Kernel C: final loss reduction ----------------
__global__ __launch_bounds__(1024) void loss_kernel(
    const float* __restrict__ rowsum1, const float* __restrict__ num1,
    const float* __restrict__ rowsum2, const float* __restrict__ num2,
    float* __restrict__ out)
{
  __shared__ float part[16];
  const int tid = threadIdx.x, lane = tid & 63, w = tid >> 6;
  float acc = 0.f;
  for (int i = tid; i < N; i += 1024) {
    float sc = -logf(num1[i]/(rowsum1[i]+1e-8f) + 1e-8f);
    float mp = -logf(num2[i]/(rowsum2[i]+1e-8f) + 1e-8f);
    acc += 0.5f*sc + 0.5f*mp;   // LAMBDA = 0.5
  }
  #pragma unroll
  for (int m = 1; m < 64; m <<= 1) acc += __shfl_xor(acc, m);
  if (lane == 0) part[w] = acc;
  __syncthreads();
  if (tid == 0) {
    float t = 0.f;
    #pragma unroll
    for (int k = 0; k < 16; ++k) t += part[k];
    out[0] = t * (1.0f/N);
  }
}

extern "C" void kernel_launch(void* const* d_in, const int* in_sizes, int n_in,
                              void* d_out, int out_size, void* d_ws, size_t ws_size,
                              hipStream_t stream) {
  const float* x1  = (const float*)d_in[0];
  const float* x2  = (const float*)d_in[1];
  const float* W1  = (const float*)d_in[2];
  const float* b1  = (const float*)d_in[3];
  const float* W2  = (const float*)d_in[4];
  const float* b2  = (const float*)d_in[5];
  const float* pos = (const float*)d_in[6];

  char* ws = (char*)d_ws;
  __bf16* Z1h = (__bf16*)ws;
  __bf16* Z2h = (__bf16*)(ws + (size_t)N*HID*sizeof(__bf16));
  size_t zbytes = (size_t)2*N*HID*sizeof(__bf16);   // 2 MB
  float* rowsum1 = (float*)(ws + zbytes);
  float* num1    = rowsum1 + N;
  float* rowsum2 = num1 + N;
  float* num2    = rowsum2 + N;

  hipMemsetAsync(ws + zbytes, 0, (size_t)4*N*sizeof(float), stream);
  proj_kernel<<<1024, 256, 0, stream>>>(x1, x2, W1, b1, W2, b2, Z1h, Z2h);
  sim_kernel<<<128*JC, 256, 0, stream>>>(Z1h, Z2h, pos, rowsum1, num1, rowsum2, num2);
  loss_kernel<<<1, 1024, 0, stream>>>(rowsum1, num1, rowsum2, num2, (float*)d_out);
}